// Round 14
// baseline (200.242 us; speedup 1.0000x reference)
//
#include <hip/hip_runtime.h>

#define BQ 2
#define DIMC 192
#define DINNER 384
#define LQ 4096
#define NST 16
#define XDBLP 48
#define NCHUNK 256
#define CS 16            // LQ / NCHUNK
#define USP 388          // padded us stride: 388 % 32 = 4 -> bank-conflict-free
#define PANEL 8          // k1: W c-rows per LDS panel

// ---------------- K0: W_x -> WxI[d/4][k][4] (zero-padded), W_out -> WoutT[384][192] -
__global__ void k0_transpose(const float* __restrict__ Wx, const float* __restrict__ Wout,
                             float* __restrict__ WxI, float* __restrict__ WoutT) {
    int t = blockIdx.x * 256 + threadIdx.x;
    if (t < DINNER * XDBLP) {
        int d = t / XDBLP, k = t % XDBLP;
        float v = (k < 44) ? Wx[k * DINNER + d] : 0.f;
        WxI[(d >> 2) * (XDBLP * 4) + k * 4 + (d & 3)] = v;
    }
    if (t < DINNER * DIMC) {
        int d = t / DIMC, c = t % DIMC;
        WoutT[t] = Wout[c * DINNER + d];   // WoutT[d][c]
    }
}

// ---------------- K1: xz = xf @ W_in — LDS-staged W panels, double-buffered ---------
// grid (128 lb, 3 mb, 2 b), block 256 = 4 waves. Tile 32 l x 256 m; wave owns
// l-octet; lane owns m-planes {lane, lane+64, lane+128, lane+192}.
// Per panel (8 c): 2 staging dwordx4/thread (shared by all waves) + 1 barrier;
// per c: 4 conflict-free b32 (W) + 2 uniform b128 (x) + 32 FMA.
__global__ __launch_bounds__(256) void k1_inproj(const float* __restrict__ x,
                                                 const float* __restrict__ W_in,
                                                 float* __restrict__ xz) {
    __shared__ float xs[DIMC * 32];        // 24 KB, [c][ll]
    __shared__ float ws[2][PANEL * 256];   // 2 x 8 KB W panels [c_local][m]
    int b = blockIdx.z, lb = blockIdx.x, mb = blockIdx.y;
    int t = threadIdx.x;
    int l0 = lb * 32;
    const float* xb = x + (size_t)b * DIMC * LQ + l0;
    #pragma unroll
    for (int it = 0; it < 24; ++it) {
        int e = it * 256 + t;                // 6144 = 192*32
        int c = e >> 5, ll = e & 31;
        xs[e] = xb[(size_t)c * LQ + ll];
    }
    int m0 = mb * 256;
    const float* Wb = W_in + m0;
    int sr = t >> 5;            // staging row 0..7
    int sm = (t & 31) * 8;      // staging m offset
    {   // stage panel 0
        const float* src = Wb + (size_t)sr * 768 + sm;
        *(float4*)(&ws[0][sr * 256 + sm])     = *(const float4*)(src);
        *(float4*)(&ws[0][sr * 256 + sm + 4]) = *(const float4*)(src + 4);
    }
    __syncthreads();
    int lane = t & 63;
    int wq = __builtin_amdgcn_readfirstlane(t >> 6);   // wave's l-octet
    float4 acc[8];   // acc[j].x/.y/.z/.w = m-planes 0..3 for l = l0+wq*8+j
    #pragma unroll
    for (int j = 0; j < 8; ++j) acc[j] = make_float4(0.f, 0.f, 0.f, 0.f);
    for (int p = 0; p < DIMC / PANEL; ++p) {
        int buf = p & 1;
        float4 pre0, pre1;
        if (p < DIMC / PANEL - 1) {   // prefetch next panel into registers
            const float* src = Wb + (size_t)((p + 1) * PANEL + sr) * 768 + sm;
            pre0 = *(const float4*)(src);
            pre1 = *(const float4*)(src + 4);
        }
        #pragma unroll
        for (int cc = 0; cc < PANEL; ++cc) {
            int c = p * PANEL + cc;
            float w0 = ws[buf][cc * 256 + lane];           // stride-1: conflict-free
            float w1 = ws[buf][cc * 256 + 64 + lane];
            float w2 = ws[buf][cc * 256 + 128 + lane];
            float w3 = ws[buf][cc * 256 + 192 + lane];
            float4 xa = *(const float4*)(xs + c * 32 + wq * 8);       // uniform
            float4 xc = *(const float4*)(xs + c * 32 + wq * 8 + 4);
            #define K1FMA(J, XV) \
                acc[J].x = fmaf(w0, XV, acc[J].x); acc[J].y = fmaf(w1, XV, acc[J].y); \
                acc[J].z = fmaf(w2, XV, acc[J].z); acc[J].w = fmaf(w3, XV, acc[J].w);
            K1FMA(0, xa.x) K1FMA(1, xa.y) K1FMA(2, xa.z) K1FMA(3, xa.w)
            K1FMA(4, xc.x) K1FMA(5, xc.y) K1FMA(6, xc.z) K1FMA(7, xc.w)
            #undef K1FMA
        }
        if (p < DIMC / PANEL - 1) {   // write prefetched panel to the other buffer
            *(float4*)(&ws[buf ^ 1][sr * 256 + sm])     = pre0;
            *(float4*)(&ws[buf ^ 1][sr * 256 + sm + 4]) = pre1;
        }
        __syncthreads();   // next iter reads buf^1; prev readers of buf are done
    }
    #pragma unroll
    for (int j = 0; j < 8; ++j) {
        float* dst = xz + (size_t)(b * LQ + l0 + wq * 8 + j) * 768 + m0 + lane;
        dst[0]   = acc[j].x;
        dst[64]  = acc[j].y;
        dst[128] = acc[j].z;
        dst[192] = acc[j].w;
    }
}

// ---------------- KA: fused conv+silu -> x_dbl -> scan pass A -----------------------
// grid (256 ch, 2 b), block 384 (thread = d). u kept in LDS only.
__global__ __launch_bounds__(DINNER) void kA_fused(const float* __restrict__ xz,
                                                   const float* __restrict__ conv_w,
                                                   const float* __restrict__ conv_b,
                                                   const float* __restrict__ WxI,
                                                   const float* __restrict__ W_dt,
                                                   const float* __restrict__ b_dt,
                                                   const float* __restrict__ A_log,
                                                   const float* __restrict__ Dp,
                                                   float* __restrict__ hend,
                                                   float* __restrict__ sumd,
                                                   float* __restrict__ sdcg,
                                                   float* __restrict__ ypart,
                                                   float* __restrict__ xdC) {
    __shared__ float us[CS * USP];      // 24.8 KB: u tile [ll][d], padded stride
    __shared__ float xd[CS * XDBLP];    //  3.0 KB: x_dbl tile [ll][48]
    int b = blockIdx.y, ch = blockIdx.x;
    int l0 = ch * CS;
    int t = threadIdx.x;   // = d
    float4 cw = *(const float4*)(conv_w + t * 4);
    float bias = conv_b[t];
    float xm3 = 0.f, xm2 = 0.f, xm1 = 0.f;
    #pragma unroll
    for (int i = 3; i >= 1; --i) {
        int l = l0 - i;
        float v = (l >= 0) ? xz[(size_t)(b * LQ + l) * 768 + t] : 0.f;
        xm3 = xm2; xm2 = xm1; xm1 = v;
    }
    #pragma unroll
    for (int ll = 0; ll < CS; ++ll) {
        float v = xz[(size_t)(b * LQ + l0 + ll) * 768 + t];
        float a = bias;
        a = fmaf(cw.x, xm3, a);
        a = fmaf(cw.y, xm2, a);
        a = fmaf(cw.z, xm1, a);
        a = fmaf(cw.w, v, a);
        us[ll * USP + t] = a / (1.f + __expf(-a));   // silu, LDS only
        xm3 = xm2; xm2 = xm1; xm1 = v;
    }
    __syncthreads();
    {
        int l = t / XDBLP;        // 0..7
        int k = t % XDBLP;
        float a0 = 0.f, a1 = 0.f;
        const float* WI = WxI + k * 4;
        const float* u0p = us + l * USP;
        const float* u1p = us + (l + 8) * USP;
        #pragma unroll 4
        for (int dq = 0; dq < 96; ++dq) {
            float4 wq = *(const float4*)(WI + dq * (XDBLP * 4));   // W[4dq..4dq+3][k]
            float4 u0 = *(const float4*)(u0p + dq * 4);
            float4 u1 = *(const float4*)(u1p + dq * 4);
            a0 = fmaf(u0.x, wq.x, fmaf(u0.y, wq.y, fmaf(u0.z, wq.z, fmaf(u0.w, wq.w, a0))));
            a1 = fmaf(u1.x, wq.x, fmaf(u1.y, wq.y, fmaf(u1.z, wq.z, fmaf(u1.w, wq.w, a1))));
        }
        xd[l * XDBLP + k] = a0;
        xd[(l + 8) * XDBLP + k] = a1;
        if (k >= 28 && k < 44) {   // C columns for pass C
            xdC[(size_t)(b * LQ + l0 + l) * NST + (k - 28)] = a0;
            xdC[(size_t)(b * LQ + l0 + l + 8) * NST + (k - 28)] = a1;
        }
    }
    __syncthreads();
    float wdt[12];
    #pragma unroll
    for (int r = 0; r < 12; r += 4) {
        float4 v = *(const float4*)(W_dt + t * 12 + r);
        wdt[r] = v.x; wdt[r+1] = v.y; wdt[r+2] = v.z; wdt[r+3] = v.w;
    }
    float bdt2 = 2.f * b_dt[t];
    float Dd = Dp[t];
    float A[NST];
    #pragma unroll
    for (int n = 0; n < NST; ++n) A[n] = -__expf(A_log[t * NST + n]);
    float h[NST];
    #pragma unroll
    for (int n = 0; n < NST; ++n) h[n] = 0.f;
    float sd = 0.f;
    #pragma unroll 4
    for (int ll = 0; ll < CS; ++ll) {
        size_t gi = (size_t)(b * LQ + l0 + ll) * DINNER + t;
        float u = us[ll * USP + t];   // re-read from LDS (stride-1, conflict-free)
        float d0 = bdt2, d1 = 0.f, d2 = 0.f;
        #pragma unroll
        for (int r = 0; r < 4; ++r) {
            d0 = fmaf(xd[ll * XDBLP + r], wdt[r], d0);
            d1 = fmaf(xd[ll * XDBLP + 4 + r], wdt[4 + r], d1);
            d2 = fmaf(xd[ll * XDBLP + 8 + r], wdt[8 + r], d2);
        }
        float dr = d0 + d1 + d2;
        float dl = fmaxf(dr, 0.f) + __logf(1.f + __expf(-fabsf(dr)));   // softplus
        sd += dl;
        sdcg[gi] = sd;
        float du = dl * u;
        float yv = 0.f;
        #pragma unroll
        for (int n = 0; n < NST; ++n) {
            h[n] = fmaf(__expf(dl * A[n]), h[n], du * xd[ll * XDBLP + 12 + n]);
            yv = fmaf(h[n], xd[ll * XDBLP + 28 + n], yv);
        }
        ypart[gi] = fmaf(u, Dd, yv);   // fold u*D here
    }
    size_t hb = ((size_t)(b * NCHUNK + ch) * DINNER + t) * NST;
    #pragma unroll
    for (int n = 0; n < NST; n += 4)
        *(float4*)(hend + hb + n) = make_float4(h[n], h[n+1], h[n+2], h[n+3]);
    sumd[(size_t)(b * NCHUNK + ch) * DINNER + t] = sd;
}

// ---------------- K6: chunk-carry combine, 16 segments x 16 chunks ------------------
__global__ __launch_bounds__(256) void k6_combine(const float* __restrict__ A_log,
                                                  const float* __restrict__ sumd,
                                                  const float* __restrict__ hend,
                                                  float* __restrict__ hin) {
    __shared__ float As[16][NST], Bs[16][NST];
    int d = blockIdx.x, b = blockIdx.y;
    int t = threadIdx.x;
    int n = t & 15, g = t >> 4;
    float A = -__expf(A_log[d * NST + n]);
    float av[16], bh[16];
    float ca = 1.f, cb = 0.f;
    #pragma unroll
    for (int i = 0; i < 16; ++i) {
        int ch = g * 16 + i;
        av[i] = __expf(A * sumd[(size_t)(b * NCHUNK + ch) * DINNER + d]);
        bh[i] = hend[((size_t)(b * NCHUNK + ch) * DINNER + d) * NST + n];
        ca *= av[i];
        cb = fmaf(av[i], cb, bh[i]);
    }
    As[g][n] = ca; Bs[g][n] = cb;
    __syncthreads();
    float carry = 0.f;                       // h0 = 0
    for (int j = 0; j < g; ++j) carry = fmaf(As[j][n], carry, Bs[j][n]);
    #pragma unroll
    for (int i = 0; i < 16; ++i) {
        int ch = g * 16 + i;
        hin[((size_t)(b * NCHUNK + ch) * DINNER + d) * NST + n] = carry;
        carry = fmaf(av[i], carry, bh[i]);
    }
}

// ---------------- KC1: pass C correction + gate -> yT[b,d,l] ------------------------
__global__ __launch_bounds__(DINNER) void kC1_passC(const float* __restrict__ xz,
                                                    const float* __restrict__ xdC,
                                                    const float* __restrict__ A_log,
                                                    const float* __restrict__ hin,
                                                    const float* __restrict__ sdcg,
                                                    const float* __restrict__ ypart,
                                                    float* __restrict__ yT) {
    __shared__ float cxd[CS * NST];        // C rows, 1 KB
    __shared__ float ys[CS * DINNER];      // 24.6 KB
    int b = blockIdx.y, ch = blockIdx.x;
    int l0 = ch * CS;
    int t = threadIdx.x;
    for (int idx = t; idx < CS * NST; idx += DINNER)
        cxd[idx] = xdC[(size_t)(b * LQ + l0 + (idx >> 4)) * NST + (idx & 15)];
    float A[NST];
    #pragma unroll
    for (int n = 0; n < NST; ++n) A[n] = -__expf(A_log[t * NST + n]);
    float carry[NST];
    size_t hb = ((size_t)(b * NCHUNK + ch) * DINNER + t) * NST;
    #pragma unroll
    for (int n = 0; n < NST; n += 4) {
        float4 v = *(const float4*)(hin + hb + n);
        carry[n] = v.x; carry[n+1] = v.y; carry[n+2] = v.z; carry[n+3] = v.w;
    }
    __syncthreads();
    #pragma unroll 4
    for (int ll = 0; ll < CS; ++ll) {
        size_t gi = (size_t)(b * LQ + l0 + ll) * DINNER + t;
        size_t zr = (size_t)(b * LQ + l0 + ll) * 768 + 384 + t;
        float yv = ypart[gi];   // includes u*D
        float sc = sdcg[gi];
        float z  = xz[zr];
        #pragma unroll
        for (int n = 0; n < NST; ++n)
            yv = fmaf(__expf(A[n] * sc) * carry[n], cxd[ll * NST + n], yv);
        float sig = 1.f / (1.f + __expf(-z));
        ys[ll * DINNER + t] = yv * (z * sig);
    }
    __syncthreads();
    float* dst = yT + ((size_t)(b * DINNER) + t) * LQ + l0;
    #pragma unroll
    for (int q = 0; q < CS; q += 4) {
        float4 v = make_float4(ys[(q+0) * DINNER + t], ys[(q+1) * DINNER + t],
                               ys[(q+2) * DINNER + t], ys[(q+3) * DINNER + t]);
        *(float4*)(dst + q) = v;
    }
}

// ---------------- K8: out partials — 32-l tile, wave owns l-octet, split-K=2 --------
__global__ __launch_bounds__(256) void k8_out(const float* __restrict__ yT,
                                              const float* __restrict__ WoutT,
                                              float* __restrict__ op0,
                                              float* __restrict__ op1) {
    __shared__ float yt[DIMC * 33];   // 25.3 KB; stage [d][ll] (192x32), transpose [c*33+ll]
    int lt = blockIdx.x, ds = blockIdx.y, b = blockIdx.z;
    int l0 = lt * 32;
    int t = threadIdx.x;
    const float* yb = yT + (size_t)(b * DINNER + ds * 192) * LQ + l0;
    #pragma unroll
    for (int it = 0; it < 24; ++it) {
        int e = it * 256 + t;                // 6144 = 192*32
        int d = e >> 5, ll = e & 31;
        yt[d * 32 + ll] = yb[(size_t)d * LQ + ll];
    }
    __syncthreads();
    int lane = t & 63;
    int wq = __builtin_amdgcn_readfirstlane(t >> 6);   // wave's l-octet
    float acc[8][3];
    #pragma unroll
    for (int j = 0; j < 8; ++j)
        #pragma unroll
        for (int k = 0; k < 3; ++k) acc[j][k] = 0.f;
    const float* Wb = WoutT + (size_t)(ds * 192) * DIMC + lane;
    #pragma unroll 4
    for (int d = 0; d < 192; ++d) {
        float4 ya = *(const float4*)(yt + d * 32 + wq * 8);       // uniform broadcast
        float4 yc = *(const float4*)(yt + d * 32 + wq * 8 + 4);
        float w0 = Wb[(size_t)d * DIMC];
        float w1 = Wb[(size_t)d * DIMC + 64];
        float w2 = Wb[(size_t)d * DIMC + 128];
        acc[0][0] = fmaf(w0, ya.x, acc[0][0]); acc[0][1] = fmaf(w1, ya.x, acc[0][1]); acc[0][2] = fmaf(w2, ya.x, acc[0][2]);
        acc[1][0] = fmaf(w0, ya.y, acc[1][0]); acc[1][1] = fmaf(w1, ya.y, acc[1][1]); acc[1][2] = fmaf(w2, ya.y, acc[1][2]);
        acc[2][0] = fmaf(w0, ya.z, acc[2][0]); acc[2][1] = fmaf(w1, ya.z, acc[2][1]); acc[2][2] = fmaf(w2, ya.z, acc[2][2]);
        acc[3][0] = fmaf(w0, ya.w, acc[3][0]); acc[3][1] = fmaf(w1, ya.w, acc[3][1]); acc[3][2] = fmaf(w2, ya.w, acc[3][2]);
        acc[4][0] = fmaf(w0, yc.x, acc[4][0]); acc[4][1] = fmaf(w1, yc.x, acc[4][1]); acc[4][2] = fmaf(w2, yc.x, acc[4][2]);
        acc[5][0] = fmaf(w0, yc.y, acc[5][0]); acc[5][1] = fmaf(w1, yc.y, acc[5][1]); acc[5][2] = fmaf(w2, yc.y, acc[5][2]);
        acc[6][0] = fmaf(w0, yc.z, acc[6][0]); acc[6][1] = fmaf(w1, yc.z, acc[6][1]); acc[6][2] = fmaf(w2, yc.z, acc[6][2]);
        acc[7][0] = fmaf(w0, yc.w, acc[7][0]); acc[7][1] = fmaf(w1, yc.w, acc[7][1]); acc[7][2] = fmaf(w2, yc.w, acc[7][2]);
    }
    __syncthreads();   // done reading stage layout
    #pragma unroll
    for (int k = 0; k < 3; ++k)
        #pragma unroll
        for (int j = 0; j < 8; ++j)
            yt[(lane + 64 * k) * 33 + wq * 8 + j] = acc[j][k];   // stride-33: conflict-free
    __syncthreads();
    float* op = ds ? op1 : op0;
    #pragma unroll
    for (int it = 0; it < 24; ++it) {
        int e = it * 256 + t;                // 6144 = 192 c x 32 l
        int c = e >> 5, ll = e & 31;
        op[((size_t)b * DIMC + c) * LQ + l0 + ll] = yt[c * 33 + ll];
    }
}

// ---------------- K9: out = op0 + op1 ----------------------------------------------
__global__ __launch_bounds__(256) void k9_sum(const float* __restrict__ op0,
                                              const float* __restrict__ op1,
                                              float* __restrict__ out) {
    size_t i = ((size_t)blockIdx.x * 256 + threadIdx.x) * 4;
    float4 a = *(const float4*)(op0 + i);
    float4 c = *(const float4*)(op1 + i);
    *(float4*)(out + i) = make_float4(a.x + c.x, a.y + c.y, a.z + c.z, a.w + c.w);
}

extern "C" void kernel_launch(void* const* d_in, const int* in_sizes, int n_in,
                              void* d_out, int out_size, void* d_ws, size_t ws_size,
                              hipStream_t stream) {
    const float* x      = (const float*)d_in[0];
    const float* W_in   = (const float*)d_in[1];
    const float* conv_w = (const float*)d_in[2];
    const float* conv_b = (const float*)d_in[3];
    const float* W_x    = (const float*)d_in[4];
    const float* W_dt   = (const float*)d_in[5];
    const float* b_dt   = (const float*)d_in[6];
    const float* A_log  = (const float*)d_in[7];
    const float* Dp     = (const float*)d_in[8];
    const float* W_out  = (const float*)d_in[9];
    float* outp = (float*)d_out;

    const size_t NBL = (size_t)BQ * LQ * DINNER;     // 3,145,728
    float* w = (float*)d_ws;
    float* xz    = w; w += (size_t)BQ * LQ * 768;    // 6,291,456
    float* hend  = w; w += (size_t)BQ * NCHUNK * DINNER * NST;
    float* hin   = w; w += (size_t)BQ * NCHUNK * DINNER * NST;
    float* sumd  = w; w += (size_t)BQ * NCHUNK * DINNER;
    float* sdcg  = w; w += NBL;
    float* ypart = w; w += NBL;
    float* xdC   = w; w += (size_t)BQ * LQ * NST;    //   131,072
    float* yT    = w; w += NBL;
    float* op0   = w; w += (size_t)BQ * DIMC * LQ;
    float* op1   = w; w += (size_t)BQ * DIMC * LQ;
    float* WxI   = w; w += (size_t)DINNER * XDBLP;
    float* WoutT = w; w += (size_t)DINNER * DIMC;

    k0_transpose<<<288, 256, 0, stream>>>(W_x, W_out, WxI, WoutT);
    k1_inproj<<<dim3(128, 3, BQ), 256, 0, stream>>>(x, W_in, xz);
    kA_fused<<<dim3(NCHUNK, BQ), DINNER, 0, stream>>>(xz, conv_w, conv_b, WxI, W_dt,
                                                      b_dt, A_log, Dp,
                                                      hend, sumd, sdcg, ypart, xdC);
    k6_combine<<<dim3(DINNER, BQ), 256, 0, stream>>>(A_log, sumd, hend, hin);
    kC1_passC<<<dim3(NCHUNK, BQ), DINNER, 0, stream>>>(xz, xdC, A_log, hin, sdcg,
                                                       ypart, yT);
    k8_out<<<dim3(128, 2, BQ), 256, 0, stream>>>(yT, WoutT, op0, op1);
    k9_sum<<<(BQ * DIMC * LQ) / 1024, 256, 0, stream>>>(op0, op1, outp);
}

// Round 15
// 196.319 us; speedup vs baseline: 1.0200x; 1.0200x over previous
//
#include <hip/hip_runtime.h>

#define BQ 2
#define DIMC 192
#define DINNER 384
#define LQ 4096
#define NST 16
#define XDBLP 48
#define NCHUNK 256
#define CS 16            // LQ / NCHUNK
#define USP 388          // padded us stride: 388 % 32 = 4 -> bank-conflict-free

// ---------------- K0: W_x -> WxI[d/4][k][4] (zero-padded), W_out -> WoutT[384][192] -
__global__ void k0_transpose(const float* __restrict__ Wx, const float* __restrict__ Wout,
                             float* __restrict__ WxI, float* __restrict__ WoutT) {
    int t = blockIdx.x * 256 + threadIdx.x;
    if (t < DINNER * XDBLP) {
        int d = t / XDBLP, k = t % XDBLP;
        float v = (k < 44) ? Wx[k * DINNER + d] : 0.f;
        WxI[(d >> 2) * (XDBLP * 4) + k * 4 + (d & 3)] = v;
    }
    if (t < DINNER * DIMC) {
        int d = t / DIMC, c = t % DIMC;
        WoutT[t] = Wout[c * DINNER + d];   // WoutT[d][c]
    }
}

// ---------------- K1: xz = xf @ W_in — R6 structure (32-l tile, 4 waves x 8 acc) ----
// Verified local optimum (R6/R13 ~42 us): per c-iter 1 coalesced dwordx4 W-load +
// 2 uniform b128 x-reads + 32 FMA; 768 blocks. Perturbations all regress.
__global__ __launch_bounds__(256) void k1_inproj(const float* __restrict__ x,
                                                 const float* __restrict__ W_in,
                                                 float* __restrict__ xz) {
    __shared__ float xs[DIMC * 32];   // 24 KB, [c][ll]
    int b = blockIdx.z, lb = blockIdx.x, mb = blockIdx.y;
    int t = threadIdx.x;
    int l0 = lb * 32;
    const float* xb = x + (size_t)b * DIMC * LQ + l0;
    #pragma unroll
    for (int it = 0; it < 24; ++it) {
        int e = it * 256 + t;                // 6144 = 192*32
        int c = e >> 5, ll = e & 31;
        xs[e] = xb[(size_t)c * LQ + ll];
    }
    __syncthreads();
    int lane = t & 63;
    int wq = __builtin_amdgcn_readfirstlane(t >> 6);   // wave's l-octet
    int m0 = mb * 256 + lane * 4;
    float4 acc[8];
    #pragma unroll
    for (int j = 0; j < 8; ++j) acc[j] = make_float4(0.f, 0.f, 0.f, 0.f);
    const float* Wb = W_in + m0;
    #pragma unroll 4
    for (int c = 0; c < DIMC; ++c) {
        float4 wv = *(const float4*)(Wb + (size_t)c * 768);   // coalesced 1KB/wave
        float4 xa = *(const float4*)(xs + c * 32 + wq * 8);   // uniform broadcast
        float4 xc = *(const float4*)(xs + c * 32 + wq * 8 + 4);
        #define K1FMA(J, XV) \
            acc[J].x = fmaf(wv.x, XV, acc[J].x); acc[J].y = fmaf(wv.y, XV, acc[J].y); \
            acc[J].z = fmaf(wv.z, XV, acc[J].z); acc[J].w = fmaf(wv.w, XV, acc[J].w);
        K1FMA(0, xa.x) K1FMA(1, xa.y) K1FMA(2, xa.z) K1FMA(3, xa.w)
        K1FMA(4, xc.x) K1FMA(5, xc.y) K1FMA(6, xc.z) K1FMA(7, xc.w)
        #undef K1FMA
    }
    #pragma unroll
    for (int j = 0; j < 8; ++j)
        *(float4*)(xz + (size_t)(b * LQ + l0 + wq * 8 + j) * 768 + m0) = acc[j];
}

// ---------------- KA: fused conv+silu -> x_dbl -> scan pass A -----------------------
// grid (256 ch, 2 b), block 384 (thread = d). u kept in LDS only.
// Emits ypsd = interleaved (ypart, sdc) float2 — one dwordx2 store per (l,d).
__global__ __launch_bounds__(DINNER) void kA_fused(const float* __restrict__ xz,
                                                   const float* __restrict__ conv_w,
                                                   const float* __restrict__ conv_b,
                                                   const float* __restrict__ WxI,
                                                   const float* __restrict__ W_dt,
                                                   const float* __restrict__ b_dt,
                                                   const float* __restrict__ A_log,
                                                   const float* __restrict__ Dp,
                                                   float* __restrict__ hend,
                                                   float* __restrict__ sumd,
                                                   float* __restrict__ ypsd,
                                                   float* __restrict__ xdC) {
    __shared__ float us[CS * USP];      // 24.8 KB: u tile [ll][d], padded stride
    __shared__ float xd[CS * XDBLP];    //  3.0 KB: x_dbl tile [ll][48]
    int b = blockIdx.y, ch = blockIdx.x;
    int l0 = ch * CS;
    int t = threadIdx.x;   // = d
    float4 cw = *(const float4*)(conv_w + t * 4);
    float bias = conv_b[t];
    float xm3 = 0.f, xm2 = 0.f, xm1 = 0.f;
    #pragma unroll
    for (int i = 3; i >= 1; --i) {
        int l = l0 - i;
        float v = (l >= 0) ? xz[(size_t)(b * LQ + l) * 768 + t] : 0.f;
        xm3 = xm2; xm2 = xm1; xm1 = v;
    }
    #pragma unroll
    for (int ll = 0; ll < CS; ++ll) {
        float v = xz[(size_t)(b * LQ + l0 + ll) * 768 + t];
        float a = bias;
        a = fmaf(cw.x, xm3, a);
        a = fmaf(cw.y, xm2, a);
        a = fmaf(cw.z, xm1, a);
        a = fmaf(cw.w, v, a);
        us[ll * USP + t] = a / (1.f + __expf(-a));   // silu, LDS only
        xm3 = xm2; xm2 = xm1; xm1 = v;
    }
    __syncthreads();
    {
        int l = t / XDBLP;        // 0..7
        int k = t % XDBLP;
        float a0 = 0.f, a1 = 0.f;
        const float* WI = WxI + k * 4;
        const float* u0p = us + l * USP;
        const float* u1p = us + (l + 8) * USP;
        #pragma unroll 4
        for (int dq = 0; dq < 96; ++dq) {
            float4 wq = *(const float4*)(WI + dq * (XDBLP * 4));   // W[4dq..4dq+3][k]
            float4 u0 = *(const float4*)(u0p + dq * 4);
            float4 u1 = *(const float4*)(u1p + dq * 4);
            a0 = fmaf(u0.x, wq.x, fmaf(u0.y, wq.y, fmaf(u0.z, wq.z, fmaf(u0.w, wq.w, a0))));
            a1 = fmaf(u1.x, wq.x, fmaf(u1.y, wq.y, fmaf(u1.z, wq.z, fmaf(u1.w, wq.w, a1))));
        }
        xd[l * XDBLP + k] = a0;
        xd[(l + 8) * XDBLP + k] = a1;
        if (k >= 28 && k < 44) {   // C columns for pass C
            xdC[(size_t)(b * LQ + l0 + l) * NST + (k - 28)] = a0;
            xdC[(size_t)(b * LQ + l0 + l + 8) * NST + (k - 28)] = a1;
        }
    }
    __syncthreads();
    float wdt[12];
    #pragma unroll
    for (int r = 0; r < 12; r += 4) {
        float4 v = *(const float4*)(W_dt + t * 12 + r);
        wdt[r] = v.x; wdt[r+1] = v.y; wdt[r+2] = v.z; wdt[r+3] = v.w;
    }
    float bdt2 = 2.f * b_dt[t];
    float Dd = Dp[t];
    float A[NST];
    #pragma unroll
    for (int n = 0; n < NST; ++n) A[n] = -__expf(A_log[t * NST + n]);
    float h[NST];
    #pragma unroll
    for (int n = 0; n < NST; ++n) h[n] = 0.f;
    float sd = 0.f;
    #pragma unroll 4
    for (int ll = 0; ll < CS; ++ll) {
        size_t gi = (size_t)(b * LQ + l0 + ll) * DINNER + t;
        float u = us[ll * USP + t];   // re-read from LDS (stride-1, conflict-free)
        float d0 = bdt2, d1 = 0.f, d2 = 0.f;
        #pragma unroll
        for (int r = 0; r < 4; ++r) {
            d0 = fmaf(xd[ll * XDBLP + r], wdt[r], d0);
            d1 = fmaf(xd[ll * XDBLP + 4 + r], wdt[4 + r], d1);
            d2 = fmaf(xd[ll * XDBLP + 8 + r], wdt[8 + r], d2);
        }
        float dr = d0 + d1 + d2;
        float dl = fmaxf(dr, 0.f) + __logf(1.f + __expf(-fabsf(dr)));   // softplus
        sd += dl;
        float du = dl * u;
        float yv = 0.f;
        #pragma unroll
        for (int n = 0; n < NST; ++n) {
            h[n] = fmaf(__expf(dl * A[n]), h[n], du * xd[ll * XDBLP + 12 + n]);
            yv = fmaf(h[n], xd[ll * XDBLP + 28 + n], yv);
        }
        *(float2*)(ypsd + gi * 2) = make_float2(fmaf(u, Dd, yv), sd);   // one dwordx2
    }
    size_t hb = ((size_t)(b * NCHUNK + ch) * DINNER + t) * NST;
    #pragma unroll
    for (int n = 0; n < NST; n += 4)
        *(float4*)(hend + hb + n) = make_float4(h[n], h[n+1], h[n+2], h[n+3]);
    sumd[(size_t)(b * NCHUNK + ch) * DINNER + t] = sd;
}

// ---------------- K6: chunk-carry combine, 16 segments x 16 chunks ------------------
__global__ __launch_bounds__(256) void k6_combine(const float* __restrict__ A_log,
                                                  const float* __restrict__ sumd,
                                                  const float* __restrict__ hend,
                                                  float* __restrict__ hin) {
    __shared__ float As[16][NST], Bs[16][NST];
    int d = blockIdx.x, b = blockIdx.y;
    int t = threadIdx.x;
    int n = t & 15, g = t >> 4;
    float A = -__expf(A_log[d * NST + n]);
    float av[16], bh[16];
    float ca = 1.f, cb = 0.f;
    #pragma unroll
    for (int i = 0; i < 16; ++i) {
        int ch = g * 16 + i;
        av[i] = __expf(A * sumd[(size_t)(b * NCHUNK + ch) * DINNER + d]);
        bh[i] = hend[((size_t)(b * NCHUNK + ch) * DINNER + d) * NST + n];
        ca *= av[i];
        cb = fmaf(av[i], cb, bh[i]);
    }
    As[g][n] = ca; Bs[g][n] = cb;
    __syncthreads();
    float carry = 0.f;                       // h0 = 0
    for (int j = 0; j < g; ++j) carry = fmaf(As[j][n], carry, Bs[j][n]);
    #pragma unroll
    for (int i = 0; i < 16; ++i) {
        int ch = g * 16 + i;
        hin[((size_t)(b * NCHUNK + ch) * DINNER + d) * NST + n] = carry;
        carry = fmaf(av[i], carry, bh[i]);
    }
}

// ---------------- KC1: pass C correction + gate -> yT[b,d,l] ------------------------
__global__ __launch_bounds__(DINNER) void kC1_passC(const float* __restrict__ xz,
                                                    const float* __restrict__ xdC,
                                                    const float* __restrict__ A_log,
                                                    const float* __restrict__ hin,
                                                    const float* __restrict__ ypsd,
                                                    float* __restrict__ yT) {
    __shared__ float cxd[CS * NST];        // C rows, 1 KB
    __shared__ float ys[CS * DINNER];      // 24.6 KB
    int b = blockIdx.y, ch = blockIdx.x;
    int l0 = ch * CS;
    int t = threadIdx.x;
    for (int idx = t; idx < CS * NST; idx += DINNER)
        cxd[idx] = xdC[(size_t)(b * LQ + l0 + (idx >> 4)) * NST + (idx & 15)];
    float A[NST];
    #pragma unroll
    for (int n = 0; n < NST; ++n) A[n] = -__expf(A_log[t * NST + n]);
    float carry[NST];
    size_t hb = ((size_t)(b * NCHUNK + ch) * DINNER + t) * NST;
    #pragma unroll
    for (int n = 0; n < NST; n += 4) {
        float4 v = *(const float4*)(hin + hb + n);
        carry[n] = v.x; carry[n+1] = v.y; carry[n+2] = v.z; carry[n+3] = v.w;
    }
    __syncthreads();
    #pragma unroll 4
    for (int ll = 0; ll < CS; ++ll) {
        size_t gi = (size_t)(b * LQ + l0 + ll) * DINNER + t;
        size_t zr = (size_t)(b * LQ + l0 + ll) * 768 + 384 + t;
        float2 ps = *(const float2*)(ypsd + gi * 2);   // (ypart incl u*D, sdc)
        float yv = ps.x;
        float sc = ps.y;
        float z  = xz[zr];
        #pragma unroll
        for (int n = 0; n < NST; ++n)
            yv = fmaf(__expf(A[n] * sc) * carry[n], cxd[ll * NST + n], yv);
        float sig = 1.f / (1.f + __expf(-z));
        ys[ll * DINNER + t] = yv * (z * sig);
    }
    __syncthreads();
    float* dst = yT + ((size_t)(b * DINNER) + t) * LQ + l0;
    #pragma unroll
    for (int q = 0; q < CS; q += 4) {
        float4 v = make_float4(ys[(q+0) * DINNER + t], ys[(q+1) * DINNER + t],
                               ys[(q+2) * DINNER + t], ys[(q+3) * DINNER + t]);
        *(float4*)(dst + q) = v;
    }
}

// ---------------- K8: out partials — 32-l tile, wave owns l-octet, split-K=2 --------
__global__ __launch_bounds__(256) void k8_out(const float* __restrict__ yT,
                                              const float* __restrict__ WoutT,
                                              float* __restrict__ op0,
                                              float* __restrict__ op1) {
    __shared__ float yt[DIMC * 33];   // 25.3 KB; stage [d][ll] (192x32), transpose [c*33+ll]
    int lt = blockIdx.x, ds = blockIdx.y, b = blockIdx.z;
    int l0 = lt * 32;
    int t = threadIdx.x;
    const float* yb = yT + (size_t)(b * DINNER + ds * 192) * LQ + l0;
    #pragma unroll
    for (int it = 0; it < 24; ++it) {
        int e = it * 256 + t;                // 6144 = 192*32
        int d = e >> 5, ll = e & 31;
        yt[d * 32 + ll] = yb[(size_t)d * LQ + ll];
    }
    __syncthreads();
    int lane = t & 63;
    int wq = __builtin_amdgcn_readfirstlane(t >> 6);   // wave's l-octet
    float acc[8][3];
    #pragma unroll
    for (int j = 0; j < 8; ++j)
        #pragma unroll
        for (int k = 0; k < 3; ++k) acc[j][k] = 0.f;
    const float* Wb = WoutT + (size_t)(ds * 192) * DIMC + lane;
    #pragma unroll 4
    for (int d = 0; d < 192; ++d) {
        float4 ya = *(const float4*)(yt + d * 32 + wq * 8);       // uniform broadcast
        float4 yc = *(const float4*)(yt + d * 32 + wq * 8 + 4);
        float w0 = Wb[(size_t)d * DIMC];
        float w1 = Wb[(size_t)d * DIMC + 64];
        float w2 = Wb[(size_t)d * DIMC + 128];
        acc[0][0] = fmaf(w0, ya.x, acc[0][0]); acc[0][1] = fmaf(w1, ya.x, acc[0][1]); acc[0][2] = fmaf(w2, ya.x, acc[0][2]);
        acc[1][0] = fmaf(w0, ya.y, acc[1][0]); acc[1][1] = fmaf(w1, ya.y, acc[1][1]); acc[1][2] = fmaf(w2, ya.y, acc[1][2]);
        acc[2][0] = fmaf(w0, ya.z, acc[2][0]); acc[2][1] = fmaf(w1, ya.z, acc[2][1]); acc[2][2] = fmaf(w2, ya.z, acc[2][2]);
        acc[3][0] = fmaf(w0, ya.w, acc[3][0]); acc[3][1] = fmaf(w1, ya.w, acc[3][1]); acc[3][2] = fmaf(w2, ya.w, acc[3][2]);
        acc[4][0] = fmaf(w0, yc.x, acc[4][0]); acc[4][1] = fmaf(w1, yc.x, acc[4][1]); acc[4][2] = fmaf(w2, yc.x, acc[4][2]);
        acc[5][0] = fmaf(w0, yc.y, acc[5][0]); acc[5][1] = fmaf(w1, yc.y, acc[5][1]); acc[5][2] = fmaf(w2, yc.y, acc[5][2]);
        acc[6][0] = fmaf(w0, yc.z, acc[6][0]); acc[6][1] = fmaf(w1, yc.z, acc[6][1]); acc[6][2] = fmaf(w2, yc.z, acc[6][2]);
        acc[7][0] = fmaf(w0, yc.w, acc[7][0]); acc[7][1] = fmaf(w1, yc.w, acc[7][1]); acc[7][2] = fmaf(w2, yc.w, acc[7][2]);
    }
    __syncthreads();   // done reading stage layout
    #pragma unroll
    for (int k = 0; k < 3; ++k)
        #pragma unroll
        for (int j = 0; j < 8; ++j)
            yt[(lane + 64 * k) * 33 + wq * 8 + j] = acc[j][k];   // stride-33: conflict-free
    __syncthreads();
    float* op = ds ? op1 : op0;
    #pragma unroll
    for (int it = 0; it < 24; ++it) {
        int e = it * 256 + t;                // 6144 = 192 c x 32 l
        int c = e >> 5, ll = e & 31;
        op[((size_t)b * DIMC + c) * LQ + l0 + ll] = yt[c * 33 + ll];
    }
}

// ---------------- K9: out = op0 + op1 ----------------------------------------------
__global__ __launch_bounds__(256) void k9_sum(const float* __restrict__ op0,
                                              const float* __restrict__ op1,
                                              float* __restrict__ out) {
    size_t i = ((size_t)blockIdx.x * 256 + threadIdx.x) * 4;
    float4 a = *(const float4*)(op0 + i);
    float4 c = *(const float4*)(op1 + i);
    *(float4*)(out + i) = make_float4(a.x + c.x, a.y + c.y, a.z + c.z, a.w + c.w);
}

extern "C" void kernel_launch(void* const* d_in, const int* in_sizes, int n_in,
                              void* d_out, int out_size, void* d_ws, size_t ws_size,
                              hipStream_t stream) {
    const float* x      = (const float*)d_in[0];
    const float* W_in   = (const float*)d_in[1];
    const float* conv_w = (const float*)d_in[2];
    const float* conv_b = (const float*)d_in[3];
    const float* W_x    = (const float*)d_in[4];
    const float* W_dt   = (const float*)d_in[5];
    const float* b_dt   = (const float*)d_in[6];
    const float* A_log  = (const float*)d_in[7];
    const float* Dp     = (const float*)d_in[8];
    const float* W_out  = (const float*)d_in[9];
    float* outp = (float*)d_out;

    const size_t NBL = (size_t)BQ * LQ * DINNER;     // 3,145,728
    float* w = (float*)d_ws;
    float* xz    = w; w += (size_t)BQ * LQ * 768;    // 6,291,456
    float* hend  = w; w += (size_t)BQ * NCHUNK * DINNER * NST;
    float* hin   = w; w += (size_t)BQ * NCHUNK * DINNER * NST;
    float* sumd  = w; w += (size_t)BQ * NCHUNK * DINNER;
    float* ypsd  = w; w += 2 * NBL;                  // interleaved (ypart, sdc)
    float* xdC   = w; w += (size_t)BQ * LQ * NST;    //   131,072
    float* yT    = w; w += NBL;
    float* op0   = w; w += (size_t)BQ * DIMC * LQ;
    float* op1   = w; w += (size_t)BQ * DIMC * LQ;
    float* WxI   = w; w += (size_t)DINNER * XDBLP;
    float* WoutT = w; w += (size_t)DINNER * DIMC;

    k0_transpose<<<288, 256, 0, stream>>>(W_x, W_out, WxI, WoutT);
    k1_inproj<<<dim3(128, 3, BQ), 256, 0, stream>>>(x, W_in, xz);
    kA_fused<<<dim3(NCHUNK, BQ), DINNER, 0, stream>>>(xz, conv_w, conv_b, WxI, W_dt,
                                                      b_dt, A_log, Dp,
                                                      hend, sumd, ypsd, xdC);
    k6_combine<<<dim3(DINNER, BQ), 256, 0, stream>>>(A_log, sumd, hend, hin);
    kC1_passC<<<dim3(NCHUNK, BQ), DINNER, 0, stream>>>(xz, xdC, A_log, hin, ypsd, yT);
    k8_out<<<dim3(128, 2, BQ), 256, 0, stream>>>(yT, WoutT, op0, op1);
    k9_sum<<<(BQ * DIMC * LQ) / 1024, 256, 0, stream>>>(op0, op1, outp);
}